// Round 1
// 446.976 us; speedup vs baseline: 1.0133x; 1.0133x over previous
//
#include <hip/hip_runtime.h>

// TranslationRotationLoss: out = mean((tp-tt)^2 over Bx3) + mean((2*acos(clip(|dot(qp_hat,qt_hat)|,0,1)))^2 over B)
// Inputs: prediction (B,7) fp32, target (B,7) fp32. Output: 1 fp32 scalar.
// Memory-bound (448 MiB read). R3: latency-bound fix —
//   (a) 2 rows/thread + float2 LDS reads -> 28.7 KiB LDS/block -> 5 blocks/CU (62.5% occ cap,
//       was 2 blocks/CU / 25% with the 4-row 56.5 KiB tile),
//   (b) global_load_lds width-16 async staging (no VGPR round-trip, loads drain only at barrier).
// float2 LDS reads at 56*t byte stride: 16 lanes tile all 32 banks -> conflict-free.

#define TILE_F4 896    // float4s per array per tile = 512 rows * 7 floats / 4
#define BLOCK 256

__device__ __forceinline__ void load_lds16(const float4* g, float4* l) {
    // global -> LDS direct DMA, 16 bytes/lane. LDS dest must be (and is) wave-uniform
    // base + lane*16: idx = j*BLOCK + tid is lane-contiguous within each wave.
    __builtin_amdgcn_global_load_lds(
        (__attribute__((address_space(1))) void*)g,
        (__attribute__((address_space(3))) void*)l,
        16, 0, 0);
}

__global__ __launch_bounds__(BLOCK, 5) void trl_partial_kernel(
    const float* __restrict__ pred,
    const float* __restrict__ targ,
    float* __restrict__ partial,
    int ntiles,           // number of full 512-row tiles
    int ngroups,          // B/2 (total 2-row groups)
    float inv3B,          // 1/(3B)
    float invB)           // 1/B
{
    const float4* __restrict__ p4 = (const float4*)pred;
    const float4* __restrict__ t4 = (const float4*)targ;

    __shared__ float4 sp[TILE_F4];
    __shared__ float4 st[TILE_F4];

    const int tid = threadIdx.x;

    float tsum = 0.0f;  // sum of squared translation diffs
    float rsum = 0.0f;  // sum of angle^2

    for (int tile = blockIdx.x; tile < ntiles; tile += gridDim.x) {
        const int base = tile * TILE_F4;

        // --- stage: async global->LDS, perfectly coalesced, fire-and-forget ---
#pragma unroll
        for (int j = 0; j < 3; ++j) {
            const int idx = j * BLOCK + tid;
            load_lds16(&p4[base + idx], &sp[idx]);
            load_lds16(&t4[base + idx], &st[idx]);
        }
        if (tid < TILE_F4 - 3 * BLOCK) {      // 128 = waves 0,1 fully (no partial wave)
            const int idx = 3 * BLOCK + tid;
            load_lds16(&p4[base + idx], &sp[idx]);
            load_lds16(&t4[base + idx], &st[idx]);
        }
        __syncthreads();   // compiler emits s_waitcnt vmcnt(0) before s_barrier -> LDS valid

        // --- compute: thread handles rows 2*tid, 2*tid+1 (7 float2s, stride 14 floats) ---
        const float2* sp2 = (const float2*)sp;
        const float2* st2 = (const float2*)st;
        float2 pa[7], ta[7];
#pragma unroll
        for (int k = 0; k < 7; ++k) pa[k] = sp2[7 * tid + k];
#pragma unroll
        for (int k = 0; k < 7; ++k) ta[k] = st2[7 * tid + k];

        const float* pv = (const float*)pa;
        const float* tv = (const float*)ta;
#pragma unroll
        for (int j = 0; j < 2; ++j) {
            const float* p = pv + 7 * j;
            const float* t = tv + 7 * j;

            float d0 = p[0] - t[0];
            float d1 = p[1] - t[1];
            float d2 = p[2] - t[2];
            tsum += d0 * d0 + d1 * d1 + d2 * d2;

            float np2 = p[3] * p[3] + p[4] * p[4] + p[5] * p[5] + p[6] * p[6];
            float nt2 = t[3] * t[3] + t[4] * t[4] + t[5] * t[5] + t[6] * t[6];
            float dot = p[3] * t[3] + p[4] * t[4] + p[5] * t[5] + p[6] * t[6];
            float c = fabsf(dot) * rsqrtf(np2 * nt2);
            c = fminf(c, 1.0f);
            float ang = 2.0f * acosf(c);
            rsum += ang * ang;
        }
        __syncthreads();
    }

    // --- tail groups (if B not a multiple of 512): block 0, direct global path ---
    if (blockIdx.x == 0) {
        const float2* __restrict__ p2 = (const float2*)pred;
        const float2* __restrict__ t2 = (const float2*)targ;
        for (int g = ntiles * BLOCK + tid; g < ngroups; g += BLOCK) {
            float2 pa[7], ta[7];
            const long b = 7L * g;
#pragma unroll
            for (int k = 0; k < 7; ++k) pa[k] = p2[b + k];
#pragma unroll
            for (int k = 0; k < 7; ++k) ta[k] = t2[b + k];
            const float* pv = (const float*)pa;
            const float* tv = (const float*)ta;
#pragma unroll
            for (int j = 0; j < 2; ++j) {
                const float* p = pv + 7 * j;
                const float* t = tv + 7 * j;
                float d0 = p[0] - t[0], d1 = p[1] - t[1], d2 = p[2] - t[2];
                tsum += d0 * d0 + d1 * d1 + d2 * d2;
                float np2 = p[3]*p[3] + p[4]*p[4] + p[5]*p[5] + p[6]*p[6];
                float nt2 = t[3]*t[3] + t[4]*t[4] + t[5]*t[5] + t[6]*t[6];
                float dot = p[3]*t[3] + p[4]*t[4] + p[5]*t[5] + p[6]*t[6];
                float c = fminf(fabsf(dot) * rsqrtf(np2 * nt2), 1.0f);
                float ang = 2.0f * acosf(c);
                rsum += ang * ang;
            }
        }
    }

    float local = tsum * inv3B + rsum * invB;

#pragma unroll
    for (int off = 32; off > 0; off >>= 1)
        local += __shfl_down(local, off, 64);

    __shared__ float sdata[4];
    int lane = threadIdx.x & 63;
    int wave = threadIdx.x >> 6;
    if (lane == 0) sdata[wave] = local;
    __syncthreads();
    if (threadIdx.x == 0)
        partial[blockIdx.x] = sdata[0] + sdata[1] + sdata[2] + sdata[3];
}

__global__ __launch_bounds__(256) void trl_final_kernel(
    const float* __restrict__ partial, int n, float* __restrict__ out)
{
    float s = 0.0f;
    for (int i = threadIdx.x; i < n; i += 256) s += partial[i];
#pragma unroll
    for (int off = 32; off > 0; off >>= 1)
        s += __shfl_down(s, off, 64);
    __shared__ float sd[4];
    if ((threadIdx.x & 63) == 0) sd[threadIdx.x >> 6] = s;
    __syncthreads();
    if (threadIdx.x == 0) out[0] = sd[0] + sd[1] + sd[2] + sd[3];
}

extern "C" void kernel_launch(void* const* d_in, const int* in_sizes, int n_in,
                              void* d_out, int out_size, void* d_ws, size_t ws_size,
                              hipStream_t stream) {
    const float* pred = (const float*)d_in[0];
    const float* targ = (const float*)d_in[1];
    float* out = (float*)d_out;
    float* partial = (float*)d_ws;

    long long total = in_sizes[0];      // B * 7
    int B = (int)(total / 7);           // 8388608
    int ngroups = B / 2;                // 2-row groups
    int ntiles = ngroups / BLOCK;       // full 512-row tiles (16384 for B=8388608)

    float invB  = 1.0f / (float)B;
    float inv3B = invB / 3.0f;

    const int grid = 2048;              // grid-stride over 16384 tiles, 8 tiles/block

    trl_partial_kernel<<<grid, BLOCK, 0, stream>>>(pred, targ, partial, ntiles, ngroups, inv3B, invB);
    trl_final_kernel<<<1, BLOCK, 0, stream>>>(partial, grid, out);
}